// Round 3
// baseline (244.340 us; speedup 1.0000x reference)
//
#include <hip/hip_runtime.h>

#define CH 512
#define HEADS 4
#define HD 128
#define NPIX 1024
#define BATCH 16
#define GROUPS 32
#define GSZ 16
#define EPS 1e-5f

typedef _Float16 f16;
typedef _Float16 f16x8 __attribute__((ext_vector_type(8)));
typedef _Float16 f16x4 __attribute__((ext_vector_type(4)));
typedef float f32x4 __attribute__((ext_vector_type(4)));

__device__ __forceinline__ void gld16(const f16* g, f16* l) {
    __builtin_amdgcn_global_load_lds((__attribute__((address_space(1))) const void*)g,
                                     (__attribute__((address_space(3))) void*)l, 16, 0, 0);
}

// ---------------- K1: fused [groupnorm+transpose | weight-convert] ----------------
// blocks 0..511: groupnorm (one per (g,b)); blocks 512..895: weight pre-transpose.
__global__ __launch_bounds__(256, 2) void k_pre(const float* __restrict__ x, const float* __restrict__ gamma,
                                                const float* __restrict__ beta, f16* __restrict__ xnT,
                                                const float* __restrict__ wq, const float* __restrict__ wp,
                                                f16* __restrict__ wqT, f16* __restrict__ wpT) {
    __shared__ float xs[GSZ * NPIX];   // 64 KB
    __shared__ float red[8];
    __shared__ float stat2[2];
    int bidx = blockIdx.x;
    if (bidx >= 512) {
        // ---- weight convert branch ----
        int c = (bidx - 512) * 256 + threadIdx.x;
        {
            int ot = c >> 13, kbl = (c >> 7) & 63, ol = c & 127;
            const float* s = wq + ((size_t)(ot * 128 + ol)) * CH + kbl * 8;
            f32x4 a = *(const f32x4*)s, b2 = *(const f32x4*)(s + 4);
            f16x8 v;
            v[0] = (f16)a.x; v[1] = (f16)a.y; v[2] = (f16)a.z; v[3] = (f16)a.w;
            v[4] = (f16)b2.x; v[5] = (f16)b2.y; v[6] = (f16)b2.z; v[7] = (f16)b2.w;
            *(f16x8*)(wqT + (size_t)c * 8) = v;
        }
        if (c < 32768) {
            int ot = c >> 13, kbl = (c >> 7) & 63, ol = c & 127;
            const float* s = wp + ((size_t)(ot * 128 + ol)) * CH + kbl * 8;
            f32x4 a = *(const f32x4*)s, b2 = *(const f32x4*)(s + 4);
            f16x8 v;
            v[0] = (f16)a.x; v[1] = (f16)a.y; v[2] = (f16)a.z; v[3] = (f16)a.w;
            v[4] = (f16)b2.x; v[5] = (f16)b2.y; v[6] = (f16)b2.z; v[7] = (f16)b2.w;
            *(f16x8*)(wpT + (size_t)c * 8) = v;
        }
        return;
    }
    // ---- groupnorm branch ----
    int g = bidx & 31, b = bidx >> 5;
    const f32x4* x4 = (const f32x4*)(x + ((size_t)(b * GROUPS + g)) * (GSZ * NPIX));
    float s = 0.f, ss = 0.f;
    for (int i = threadIdx.x; i < GSZ * NPIX / 4; i += 256) {
        f32x4 v = x4[i];
        *(f32x4*)&xs[i * 4] = v;
        s  += v.x + v.y + v.z + v.w;
        ss += v.x * v.x + v.y * v.y + v.z * v.z + v.w * v.w;
    }
    for (int off = 32; off; off >>= 1) { s += __shfl_down(s, off); ss += __shfl_down(ss, off); }
    int wv = threadIdx.x >> 6, ln = threadIdx.x & 63;
    if (ln == 0) { red[wv] = s; red[4 + wv] = ss; }
    __syncthreads();
    if (threadIdx.x == 0) {
        float S = red[0] + red[1] + red[2] + red[3];
        float SS = red[4] + red[5] + red[6] + red[7];
        float mu = S / (GSZ * NPIX);
        float var = SS / (GSZ * NPIX) - mu * mu;
        stat2[0] = mu; stat2[1] = rsqrtf(var + EPS);
    }
    __syncthreads();
    float mu = stat2[0], rstd = stat2[1];
    int ch = threadIdx.x >> 7;
    int n  = threadIdx.x & 127;
    float gl[8], bl[8];
#pragma unroll
    for (int i = 0; i < 8; i++) {
        float gv = gamma[g * 16 + ch * 8 + i] * rstd;
        gl[i] = gv;
        bl[i] = beta[g * 16 + ch * 8 + i] - mu * gv;
    }
    f16* tb0 = xnT + ((size_t)(b * 8)) * 65536 + (g * 2 + ch) * 1024 + n * 8;
#pragma unroll
    for (int nt = 0; nt < 8; nt++) {
        f16x8 o;
#pragma unroll
        for (int i = 0; i < 8; i++)
            o[i] = (f16)(xs[(ch * 8 + i) * 1024 + nt * 128 + n] * gl[i] + bl[i]);
        *(f16x8*)(tb0 + (size_t)nt * 65536) = o;
    }
}

// ---------------- K2: QKV GEMM v1 (R10-measured), BK=64, gld16, 3 blocks/CU ----------------
__global__ __launch_bounds__(256, 3) void k_qkv(const f16* __restrict__ wT, const float* __restrict__ bias,
                                                const f16* __restrict__ xnT, f16* __restrict__ qF,
                                                f16* __restrict__ kTl, f16* __restrict__ vTl) {
    int nt = blockIdx.x, ot = blockIdx.y, b = blockIdx.z;
    int o0 = ot * 128;
    __shared__ union SM {
        struct { f16 As[8192]; f16 Bs[8192]; } s;
        f16 Cf[16384];
    } sm;
    __shared__ float biasS[128];
    if (threadIdx.x < 128) biasS[threadIdx.x] = bias[o0 + threadIdx.x];
    int tid = threadIdx.x, lane = tid & 63, wv = tid >> 6;
    int wr = wv >> 1, wc = wv & 1;
    int l15 = lane & 15, quad = lane >> 4;
    const f16* wA = wT + (size_t)ot * 65536;
    const f16* xB = xnT + ((size_t)(b * 8 + nt)) * 65536;
    f32x4 acc[4][4] = {};
    for (int kk = 0; kk < CH; kk += 64) {
        __syncthreads();
        const f16* sa = wA + (size_t)(kk >> 3) * 1024;
        const f16* sb = xB + (size_t)(kk >> 3) * 1024;
#pragma unroll
        for (int i = 0; i < 4; i++) {
            int s = wv * 4 + i;
            gld16(sa + (size_t)(s * 64 + lane) * 8, sm.s.As + s * 512);
            gld16(sb + (size_t)(s * 64 + lane) * 8, sm.s.Bs + s * 512);
        }
        __syncthreads();
#pragma unroll
        for (int dk = 0; dk < 2; dk++) {
            f16x8 af[4], bf[4];
#pragma unroll
            for (int t = 0; t < 4; t++) {
                af[t] = *(const f16x8*)(sm.s.As + (dk * 4 + quad) * 1024 + (wr * 64 + t * 16 + l15) * 8);
                bf[t] = *(const f16x8*)(sm.s.Bs + (dk * 4 + quad) * 1024 + (wc * 64 + t * 16 + l15) * 8);
            }
#pragma unroll
            for (int tm = 0; tm < 4; tm++)
#pragma unroll
                for (int tn = 0; tn < 4; tn++)
                    acc[tm][tn] = __builtin_amdgcn_mfma_f32_16x16x32_f16(af[tm], bf[tn], acc[tm][tn], 0, 0, 0);
        }
    }
    __syncthreads();
    int which = ot >> 2, h = ot & 3;
#pragma unroll
    for (int tm = 0; tm < 4; tm++)
#pragma unroll
        for (int tn = 0; tn < 4; tn++) {
            int ob = wr * 64 + tm * 16 + quad * 4;
            int n  = wc * 64 + tn * 16 + l15;
            f16x4 pv;
#pragma unroll
            for (int r = 0; r < 4; r++) pv[r] = (f16)(acc[tm][tn][r] + biasS[ob + r]);
            if (which == 0) {
                int addr = ((((n >> 5) * 2 + ((n >> 4) & 1)) * 4 + (ob >> 5)) * 512)
                         + ((ob >> 3) & 3) * 128 + (n & 15) * 8 + (quad & 1) * 4;
                *(f16x4*)&sm.Cf[addr] = pv;
            } else if (which == 1) {
                int addr = (ob >> 3) * 1024 + n * 8 + (quad & 1) * 4;
                *(f16x4*)&sm.Cf[addr] = pv;
            } else {
#pragma unroll
                for (int r = 0; r < 4; r++)
                    sm.Cf[(n >> 3) * 1024 + (ob + r) * 8 + (n & 7)] = pv[r];
            }
        }
    __syncthreads();
    f16* tb = (which == 0) ? (qF + ((size_t)((b * 4 + h) * 8 + nt)) * 16384)
            : (which == 1) ? (kTl + ((size_t)((b * 4 + h) * 8 + nt)) * 16384)
                           : (vTl + ((size_t)((b * 4 + h) * 8 + nt)) * 16384);
#pragma unroll
    for (int i = 0; i < 8; i++) {
        int cid = tid + i * 256;
        *(f16x8*)(tb + (size_t)cid * 8) = *(const f16x8*)(sm.Cf + cid * 8);
    }
}

// ---------------- K3: flash attention v9 — 32 q-rows/wave, 4-wave blocks ----------------
// LDS is the saturated pipe (R2 post-mortem): kf/vf fragment reads are q-independent,
// so doubling q-rows per wave halves LDS-read cost per MFMA (1.44 -> 0.81 instr/MFMA).
// PV back to K=32 MFMA with v1-proven b128 V-reads + XOR-swizzled wave-private P
// round-trip. 48 KB LDS, 3 blocks/CU (12 waves/CU). exp2-domain softmax + defer-max.
__global__ __launch_bounds__(256, 3) void k_attn(const f16* __restrict__ qF, const f16* __restrict__ kTl,
                                                 const f16* __restrict__ vTl, f16* __restrict__ oT) {
    __shared__ f16 smem[24576];          // [0,8192) Kl | [8192,16384) Vl | [16384,24576) P(4x2048)
    f16* Kl = smem;
    f16* Vl = smem + 8192;
    int bid = blockIdx.x;
    int nt = bid >> 6, group = bid & 63;
    int b = group >> 2, h = group & 3;
    int tid = threadIdx.x, lane = tid & 63, wv = tid >> 6;   // wv 0..3
    int l15 = lane & 15, quad = lane >> 4;
    const f16* qb = qF + ((size_t)(group * 8 + nt)) * 16384;
    const f16* kb = kTl + (size_t)group * 8 * 16384;
    const f16* vb = vTl + (size_t)group * 8 * 16384;
    f16* Pw = smem + 16384 + wv * 2048;   // wave-private 32 q x 64 k

    int srow = (wv & 1) * 8;              // staging: wv 0,1 -> Kl rows 0-7/8-15; wv 2,3 -> Vl
    bool stageK = (wv < 2);
    f16* dstL = stageK ? Kl : Vl;

    // Q fragments pre-scaled by hd^-0.5 * log2(e) (softmax in exp2 domain)
    f16x8 aq[2][4];
#pragma unroll
    for (int u = 0; u < 2; u++)
#pragma unroll
        for (int dk = 0; dk < 4; dk++) {
            f16x8 v = *(const f16x8*)(qb + ((wv * 2 + u) * 4 + dk) * 512 + lane * 8);
            aq[u][dk] = v * (f16)(0.08838834764831845f * 1.4426950408889634f);
        }

    float m_i[2] = {-1e30f, -1e30f}, l_i[2] = {0.f, 0.f};
    f32x4 oacc[2][8] = {};

    // initial staging load (K-tile 0)
    f16x8 buf[8];
    if (stageK) {
#pragma unroll
        for (int i = 0; i < 8; i++)
            buf[i] = *(const f16x8*)(kb + (size_t)(srow + i) * 1024 + lane * 8);
    } else {
#pragma unroll
        for (int i = 0; i < 8; i++)
            buf[i] = *(const f16x8*)(vb + (size_t)(srow + i) * 512 + lane * 8);
    }

    for (int mc = 0; mc < 16; mc++) {
        __syncthreads();
#pragma unroll
        for (int i = 0; i < 8; i++)
            *(f16x8*)&dstL[(srow + i) * 512 + lane * 8] = buf[i];
        __syncthreads();

        // S^T = K Q^T for both q-subtiles; kf reads shared across u
        f32x4 st[2][4] = {};
#pragma unroll
        for (int dk = 0; dk < 4; dk++) {
            f16x8 kf[4];
#pragma unroll
            for (int t = 0; t < 4; t++)
                kf[t] = *(const f16x8*)&Kl[(dk * 4 + quad) * 512 + (t * 16 + l15) * 8];
#pragma unroll
            for (int tc = 0; tc < 4; tc++) {
                st[0][tc] = __builtin_amdgcn_mfma_f32_16x16x32_f16(kf[tc], aq[0][dk], st[0][tc], 0, 0, 0);
                st[1][tc] = __builtin_amdgcn_mfma_f32_16x16x32_f16(kf[tc], aq[1][dk], st[1][tc], 0, 0, 0);
            }
        }

        // online softmax per q-subtile (exp2 domain, defer-max THR=8)
#pragma unroll
        for (int u = 0; u < 2; u++) {
            float a[4];
#pragma unroll
            for (int tc = 0; tc < 4; tc++)
                a[tc] = fmaxf(fmaxf(st[u][tc][0], st[u][tc][1]), fmaxf(st[u][tc][2], st[u][tc][3]));
            a[0] = fmaxf(a[0], a[2]); a[1] = fmaxf(a[1], a[3]);
            float mx = fmaxf(a[0], a[1]);
            mx = fmaxf(mx, __shfl_xor(mx, 16));
            mx = fmaxf(mx, __shfl_xor(mx, 32));

            bool full = !__all(mx <= m_i[u] + 8.f);
            float mnew = m_i[u], alpha = 1.f;
            if (full) {
                mnew = fmaxf(m_i[u], mx);
                alpha = __builtin_amdgcn_exp2f(m_i[u] - mnew);
                m_i[u] = mnew;
            }

            float r4[4];
#pragma unroll
            for (int tc = 0; tc < 4; tc++) {
                float p0 = __builtin_amdgcn_exp2f(st[u][tc][0] - mnew);
                float p1 = __builtin_amdgcn_exp2f(st[u][tc][1] - mnew);
                float p2 = __builtin_amdgcn_exp2f(st[u][tc][2] - mnew);
                float p3 = __builtin_amdgcn_exp2f(st[u][tc][3] - mnew);
                st[u][tc][0] = p0; st[u][tc][1] = p1;
                st[u][tc][2] = p2; st[u][tc][3] = p3;
                r4[tc] = (p0 + p1) + (p2 + p3);
            }
            float rs = (r4[0] + r4[1]) + (r4[2] + r4[3]);
            rs += __shfl_xor(rs, 16);
            rs += __shfl_xor(rs, 32);
            if (full) {
                l_i[u] = l_i[u] * alpha + rs;
#pragma unroll
                for (int tc = 0; tc < 8; tc++) {
                    oacc[u][tc].x *= alpha; oacc[u][tc].y *= alpha;
                    oacc[u][tc].z *= alpha; oacc[u][tc].w *= alpha;
                }
            } else {
                l_i[u] += rs;
            }

            // P store (wave-private, XOR-swizzled, no barrier)
#pragma unroll
            for (int tc = 0; tc < 4; tc++) {
                int blk = tc * 2 + (quad >> 1);
                f16x4 pv;
#pragma unroll
                for (int r = 0; r < 4; r++) pv[r] = (f16)st[u][tc][r];
                *(f16x4*)&Pw[(u * 16 + l15) * 64 + ((blk ^ (l15 & 7)) << 3) + ((quad & 1) << 2)] = pv;
            }
        }

        // prefetch next K/V tile
        if (mc < 15) {
            if (stageK) {
                const f16* s = kb + (size_t)((mc + 1) >> 1) * 16384 + (size_t)((mc + 1) & 1) * 512;
#pragma unroll
                for (int i = 0; i < 8; i++)
                    buf[i] = *(const f16x8*)(s + (size_t)(srow + i) * 1024 + lane * 8);
            } else {
                const f16* s = vb + (size_t)(mc + 1) * 8192;
#pragma unroll
                for (int i = 0; i < 8; i++)
                    buf[i] = *(const f16x8*)(s + (size_t)(srow + i) * 512 + lane * 8);
            }
        }

        // O^T += V^T P  (K=32 MFMA, b128 reads; vf shared across u)
#pragma unroll
        for (int mk = 0; mk < 2; mk++) {
            f16x8 pf0 = *(const f16x8*)&Pw[l15 * 64 + (((mk * 4 + quad) ^ (l15 & 7)) << 3)];
            f16x8 pf1 = *(const f16x8*)&Pw[(16 + l15) * 64 + (((mk * 4 + quad) ^ (l15 & 7)) << 3)];
#pragma unroll
            for (int t = 0; t < 8; t++) {
                f16x8 vf = *(const f16x8*)&Vl[(mk * 4 + quad) * 1024 + (t * 16 + l15) * 8];
                oacc[0][t] = __builtin_amdgcn_mfma_f32_16x16x32_f16(vf, pf0, oacc[0][t], 0, 0, 0);
                oacc[1][t] = __builtin_amdgcn_mfma_f32_16x16x32_f16(vf, pf1, oacc[1][t], 0, 0, 0);
            }
        }
    }

    // epilogue: reuse smem[0..16384) as 128x128 O-staging
    __syncthreads();
#pragma unroll
    for (int u = 0; u < 2; u++) {
        float inv = 1.f / l_i[u];
        int n = wv * 32 + u * 16 + l15;
#pragma unroll
        for (int tc = 0; tc < 8; tc++) {
            int blk = tc * 2 + (quad >> 1);
            f16x4 ov;
#pragma unroll
            for (int r = 0; r < 4; r++) ov[r] = (f16)(oacc[u][tc][r] * inv);
            *(f16x4*)&smem[n * 128 + ((blk ^ (n & 15)) << 3) + ((quad & 1) << 2)] = ov;
        }
    }
    __syncthreads();
    f16* ob = oT + ((size_t)(b * 8 + nt)) * 65536;
#pragma unroll
    for (int i = 0; i < 8; i++) {
        int cid = tid + i * 256;
        int cbl = cid >> 7, n = cid & 127;
        f16x8 v = *(const f16x8*)&smem[n * 128 + ((cbl ^ (n & 15)) << 3)];
        *(f16x8*)(ob + (size_t)(h * 16 + cbl) * 1024 + n * 8) = v;
    }
}

// ---------------- K4: proj GEMM + bias + residual -> fp32 out ----------------
__global__ __launch_bounds__(256, 3) void k_proj(const f16* __restrict__ wT, const float* __restrict__ bias,
                                                 const f16* __restrict__ oT, const float* __restrict__ x,
                                                 float* __restrict__ out) {
    int nt = blockIdx.x, ot = blockIdx.y, b = blockIdx.z;
    int n0 = nt * 128, o0 = ot * 128;
    __shared__ union SM {
        struct { f16 As[8192]; f16 Bs[8192]; } s;
        f16 Cs[128][136];
    } sm;
    __shared__ float biasS[128];
    if (threadIdx.x < 128) biasS[threadIdx.x] = bias[o0 + threadIdx.x];
    int tid = threadIdx.x, lane = tid & 63, wv = tid >> 6;
    int wr = wv >> 1, wc = wv & 1;
    int l15 = lane & 15, quad = lane >> 4;
    const f16* wA = wT + (size_t)ot * 65536;
    const f16* xB = oT + ((size_t)(b * 8 + nt)) * 65536;
    f32x4 acc[4][4] = {};
    for (int kk = 0; kk < CH; kk += 64) {
        __syncthreads();
        const f16* sa = wA + (size_t)(kk >> 3) * 1024;
        const f16* sb = xB + (size_t)(kk >> 3) * 1024;
#pragma unroll
        for (int i = 0; i < 4; i++) {
            int s = wv * 4 + i;
            gld16(sa + (size_t)(s * 64 + lane) * 8, sm.s.As + s * 512);
            gld16(sb + (size_t)(s * 64 + lane) * 8, sm.s.Bs + s * 512);
        }
        __syncthreads();
#pragma unroll
        for (int dk = 0; dk < 2; dk++) {
            f16x8 af[4], bf[4];
#pragma unroll
            for (int t = 0; t < 4; t++) {
                af[t] = *(const f16x8*)(sm.s.As + (dk * 4 + quad) * 1024 + (wr * 64 + t * 16 + l15) * 8);
                bf[t] = *(const f16x8*)(sm.s.Bs + (dk * 4 + quad) * 1024 + (wc * 64 + t * 16 + l15) * 8);
            }
#pragma unroll
            for (int tm = 0; tm < 4; tm++)
#pragma unroll
                for (int tn = 0; tn < 4; tn++)
                    acc[tm][tn] = __builtin_amdgcn_mfma_f32_16x16x32_f16(af[tm], bf[tn], acc[tm][tn], 0, 0, 0);
        }
    }
    __syncthreads();
#pragma unroll
    for (int tm = 0; tm < 4; tm++)
#pragma unroll
        for (int tn = 0; tn < 4; tn++)
#pragma unroll
            for (int r = 0; r < 4; r++) {
                int o = wr * 64 + tm * 16 + quad * 4 + r;
                int n = wc * 64 + tn * 16 + l15;
                sm.Cs[o][n] = (f16)(acc[tm][tn][r] + biasS[o]);
            }
    __syncthreads();
#pragma unroll
    for (int i = 0; i < 8; i++) {
        int cid = tid + i * 256;
        int row = cid >> 4, off = (cid & 15) * 8;
        f16x8 v = *(const f16x8*)&sm.Cs[row][off];
        size_t gofs = ((size_t)(b * CH) + o0 + row) * NPIX + n0 + off;
        const float* xp = x + gofs;
        float* op = out + gofs;
        f32x4 o0v, o1v;
        o0v.x = xp[0] + (float)v[0]; o0v.y = xp[1] + (float)v[1];
        o0v.z = xp[2] + (float)v[2]; o0v.w = xp[3] + (float)v[3];
        o1v.x = xp[4] + (float)v[4]; o1v.y = xp[5] + (float)v[5];
        o1v.z = xp[6] + (float)v[6]; o1v.w = xp[7] + (float)v[7];
        *(f32x4*)op = o0v; *(f32x4*)(op + 4) = o1v;
    }
}

extern "C" void kernel_launch(void* const* d_in, const int* in_sizes, int n_in,
                              void* d_out, int out_size, void* d_ws, size_t ws_size,
                              hipStream_t stream) {
    const float* x     = (const float*)d_in[0];
    const float* gamma = (const float*)d_in[1];
    const float* beta  = (const float*)d_in[2];
    const float* wqkv  = (const float*)d_in[3];
    const float* bqkv  = (const float*)d_in[4];
    const float* wproj = (const float*)d_in[5];
    const float* bproj = (const float*)d_in[6];
    float* out = (float*)d_out;

    char* p = (char*)d_ws;
    f16* wqT = (f16*)p;           p += (size_t)3 * CH * CH * 2;
    f16* wpT = (f16*)p;           p += (size_t)CH * CH * 2;
    f16* xnT = (f16*)p;           p += (size_t)BATCH * NPIX * CH * 2;
    f16* qF  = (f16*)p;           p += (size_t)BATCH * HEADS * NPIX * HD * 2;
    f16* kTl = (f16*)p;           p += (size_t)BATCH * HEADS * NPIX * HD * 2;
    f16* vTl = (f16*)p;           p += (size_t)BATCH * HEADS * NPIX * HD * 2;
    f16* oT  = (f16*)p;           p += (size_t)BATCH * NPIX * CH * 2;

    k_pre<<<dim3(896), 256, 0, stream>>>(x, gamma, beta, xnT, wqkv, wproj, wqT, wpT);
    k_qkv<<<dim3(8, 12, BATCH), 256, 0, stream>>>(wqT, bqkv, xnT, qF, kTl, vTl);
    k_attn<<<dim3(512), 256, 0, stream>>>(qF, kTl, vTl, oT);
    k_proj<<<dim3(8, 4, BATCH), 256, 0, stream>>>(wpT, bproj, oT, x, out);
}

// Round 4
// 196.052 us; speedup vs baseline: 1.2463x; 1.2463x over previous
//
#include <hip/hip_runtime.h>

#define CH 512
#define HEADS 4
#define HD 128
#define NPIX 1024
#define BATCH 16
#define GROUPS 32
#define GSZ 16
#define EPS 1e-5f

typedef _Float16 f16;
typedef _Float16 f16x8 __attribute__((ext_vector_type(8)));
typedef _Float16 f16x4 __attribute__((ext_vector_type(4)));
typedef float f32x4 __attribute__((ext_vector_type(4)));
typedef float f32x16 __attribute__((ext_vector_type(16)));

__device__ __forceinline__ void gld16(const f16* g, f16* l) {
    __builtin_amdgcn_global_load_lds((__attribute__((address_space(1))) const void*)g,
                                     (__attribute__((address_space(3))) void*)l, 16, 0, 0);
}

// ---------------- K1: fused [groupnorm+transpose | weight-convert] ----------------
// blocks 0..511: groupnorm (one per (g,b)); blocks 512..895: weight pre-transpose.
__global__ __launch_bounds__(256, 2) void k_pre(const float* __restrict__ x, const float* __restrict__ gamma,
                                                const float* __restrict__ beta, f16* __restrict__ xnT,
                                                const float* __restrict__ wq, const float* __restrict__ wp,
                                                f16* __restrict__ wqT, f16* __restrict__ wpT) {
    __shared__ float xs[GSZ * NPIX];   // 64 KB
    __shared__ float red[8];
    __shared__ float stat2[2];
    int bidx = blockIdx.x;
    if (bidx >= 512) {
        // ---- weight convert branch ----
        int c = (bidx - 512) * 256 + threadIdx.x;
        {
            int ot = c >> 13, kbl = (c >> 7) & 63, ol = c & 127;
            const float* s = wq + ((size_t)(ot * 128 + ol)) * CH + kbl * 8;
            f32x4 a = *(const f32x4*)s, b2 = *(const f32x4*)(s + 4);
            f16x8 v;
            v[0] = (f16)a.x; v[1] = (f16)a.y; v[2] = (f16)a.z; v[3] = (f16)a.w;
            v[4] = (f16)b2.x; v[5] = (f16)b2.y; v[6] = (f16)b2.z; v[7] = (f16)b2.w;
            *(f16x8*)(wqT + (size_t)c * 8) = v;
        }
        if (c < 32768) {
            int ot = c >> 13, kbl = (c >> 7) & 63, ol = c & 127;
            const float* s = wp + ((size_t)(ot * 128 + ol)) * CH + kbl * 8;
            f32x4 a = *(const f32x4*)s, b2 = *(const f32x4*)(s + 4);
            f16x8 v;
            v[0] = (f16)a.x; v[1] = (f16)a.y; v[2] = (f16)a.z; v[3] = (f16)a.w;
            v[4] = (f16)b2.x; v[5] = (f16)b2.y; v[6] = (f16)b2.z; v[7] = (f16)b2.w;
            *(f16x8*)(wpT + (size_t)c * 8) = v;
        }
        return;
    }
    // ---- groupnorm branch ----
    int g = bidx & 31, b = bidx >> 5;
    const f32x4* x4 = (const f32x4*)(x + ((size_t)(b * GROUPS + g)) * (GSZ * NPIX));
    float s = 0.f, ss = 0.f;
    for (int i = threadIdx.x; i < GSZ * NPIX / 4; i += 256) {
        f32x4 v = x4[i];
        *(f32x4*)&xs[i * 4] = v;
        s  += v.x + v.y + v.z + v.w;
        ss += v.x * v.x + v.y * v.y + v.z * v.z + v.w * v.w;
    }
    for (int off = 32; off; off >>= 1) { s += __shfl_down(s, off); ss += __shfl_down(ss, off); }
    int wv = threadIdx.x >> 6, ln = threadIdx.x & 63;
    if (ln == 0) { red[wv] = s; red[4 + wv] = ss; }
    __syncthreads();
    if (threadIdx.x == 0) {
        float S = red[0] + red[1] + red[2] + red[3];
        float SS = red[4] + red[5] + red[6] + red[7];
        float mu = S / (GSZ * NPIX);
        float var = SS / (GSZ * NPIX) - mu * mu;
        stat2[0] = mu; stat2[1] = rsqrtf(var + EPS);
    }
    __syncthreads();
    float mu = stat2[0], rstd = stat2[1];
    int ch = threadIdx.x >> 7;
    int n  = threadIdx.x & 127;
    float gl[8], bl[8];
#pragma unroll
    for (int i = 0; i < 8; i++) {
        float gv = gamma[g * 16 + ch * 8 + i] * rstd;
        gl[i] = gv;
        bl[i] = beta[g * 16 + ch * 8 + i] - mu * gv;
    }
    f16* tb0 = xnT + ((size_t)(b * 8)) * 65536 + (g * 2 + ch) * 1024 + n * 8;
#pragma unroll
    for (int nt = 0; nt < 8; nt++) {
        f16x8 o;
#pragma unroll
        for (int i = 0; i < 8; i++)
            o[i] = (f16)(xs[(ch * 8 + i) * 1024 + nt * 128 + n] * gl[i] + bl[i]);
        *(f16x8*)(tb0 + (size_t)nt * 65536) = o;
    }
}

// ---------------- K2: QKV GEMM v1 (R10-measured), BK=64, gld16, 3 blocks/CU ----------------
__global__ __launch_bounds__(256, 3) void k_qkv(const f16* __restrict__ wT, const float* __restrict__ bias,
                                                const f16* __restrict__ xnT, f16* __restrict__ qF,
                                                f16* __restrict__ kTl, f16* __restrict__ vTl) {
    int nt = blockIdx.x, ot = blockIdx.y, b = blockIdx.z;
    int o0 = ot * 128;
    __shared__ union SM {
        struct { f16 As[8192]; f16 Bs[8192]; } s;
        f16 Cf[16384];
    } sm;
    __shared__ float biasS[128];
    if (threadIdx.x < 128) biasS[threadIdx.x] = bias[o0 + threadIdx.x];
    int tid = threadIdx.x, lane = tid & 63, wv = tid >> 6;
    int wr = wv >> 1, wc = wv & 1;
    int l15 = lane & 15, quad = lane >> 4;
    const f16* wA = wT + (size_t)ot * 65536;
    const f16* xB = xnT + ((size_t)(b * 8 + nt)) * 65536;
    f32x4 acc[4][4] = {};
    for (int kk = 0; kk < CH; kk += 64) {
        __syncthreads();
        const f16* sa = wA + (size_t)(kk >> 3) * 1024;
        const f16* sb = xB + (size_t)(kk >> 3) * 1024;
#pragma unroll
        for (int i = 0; i < 4; i++) {
            int s = wv * 4 + i;
            gld16(sa + (size_t)(s * 64 + lane) * 8, sm.s.As + s * 512);
            gld16(sb + (size_t)(s * 64 + lane) * 8, sm.s.Bs + s * 512);
        }
        __syncthreads();
#pragma unroll
        for (int dk = 0; dk < 2; dk++) {
            f16x8 af[4], bf[4];
#pragma unroll
            for (int t = 0; t < 4; t++) {
                af[t] = *(const f16x8*)(sm.s.As + (dk * 4 + quad) * 1024 + (wr * 64 + t * 16 + l15) * 8);
                bf[t] = *(const f16x8*)(sm.s.Bs + (dk * 4 + quad) * 1024 + (wc * 64 + t * 16 + l15) * 8);
            }
#pragma unroll
            for (int tm = 0; tm < 4; tm++)
#pragma unroll
                for (int tn = 0; tn < 4; tn++)
                    acc[tm][tn] = __builtin_amdgcn_mfma_f32_16x16x32_f16(af[tm], bf[tn], acc[tm][tn], 0, 0, 0);
        }
    }
    __syncthreads();
    int which = ot >> 2, h = ot & 3;
#pragma unroll
    for (int tm = 0; tm < 4; tm++)
#pragma unroll
        for (int tn = 0; tn < 4; tn++) {
            int ob = wr * 64 + tm * 16 + quad * 4;
            int n  = wc * 64 + tn * 16 + l15;
            f16x4 pv;
#pragma unroll
            for (int r = 0; r < 4; r++) pv[r] = (f16)(acc[tm][tn][r] + biasS[ob + r]);
            if (which == 0) {
                int addr = ((((n >> 5) * 2 + ((n >> 4) & 1)) * 4 + (ob >> 5)) * 512)
                         + ((ob >> 3) & 3) * 128 + (n & 15) * 8 + (quad & 1) * 4;
                *(f16x4*)&sm.Cf[addr] = pv;
            } else if (which == 1) {
                int addr = (ob >> 3) * 1024 + n * 8 + (quad & 1) * 4;
                *(f16x4*)&sm.Cf[addr] = pv;
            } else {
#pragma unroll
                for (int r = 0; r < 4; r++)
                    sm.Cf[(n >> 3) * 1024 + (ob + r) * 8 + (n & 7)] = pv[r];
            }
        }
    __syncthreads();
    f16* tb = (which == 0) ? (qF + ((size_t)((b * 4 + h) * 8 + nt)) * 16384)
            : (which == 1) ? (kTl + ((size_t)((b * 4 + h) * 8 + nt)) * 16384)
                           : (vTl + ((size_t)((b * 4 + h) * 8 + nt)) * 16384);
#pragma unroll
    for (int i = 0; i < 8; i++) {
        int cid = tid + i * 256;
        *(f16x8*)(tb + (size_t)cid * 8) = *(const f16x8*)(sm.Cf + cid * 8);
    }
}

// ---------------- K3: flash attention v10 — 32x32 MFMA + gld16 double-buffer ----------------
// LDS-bound model: 32x32x16 MFMA halves fragment-reads/FLOP vs 16x16x32; gld16 staging
// kills the R3 spill source (buf regs) and the ds_write ops; double-buffered K/V with
// ONE barrier/iter (prefetch issued right after barrier, drained by next barrier's
// implicit vmcnt(0) after a full compute phase of flight time).
// 4 waves x 32 q-rows, 64-pix K-tiles, LDS = 2x32KB KV + 16KB P = 80KB -> 2 blocks/CU.
__global__ __launch_bounds__(256, 2) void k_attn(const f16* __restrict__ qF, const f16* __restrict__ kTl,
                                                 const f16* __restrict__ vTl, f16* __restrict__ oT) {
    extern __shared__ f16 smem[];   // [0,16384) buf0 K|V ; [16384,32768) buf1 K|V ; [32768,40960) P
    int bid = blockIdx.x;
    int nt = bid >> 6, group = bid & 63;
    int b = group >> 2, h = group & 3;
    int tid = threadIdx.x, lane = tid & 63, wv = tid >> 6;   // wv 0..3
    int l31 = lane & 31, halfl = lane >> 5;
    const f16* qb = qF + ((size_t)(group * 8 + nt)) * 16384;
    const f16* kb = kTl + (size_t)group * 8 * 16384;
    const f16* vb = vTl + (size_t)group * 8 * 16384;
    f16* Pw = smem + 32768 + wv * 2048;   // wave-private 32 q x 64 k

    // Q as B-fragments for 32x32x16: col q = wv*32 + l31, k(d) = s*16 + halfl*8 + j
    f16x8 aq[8];
    {
        int bq = (wv * 2 + ((lane >> 4) & 1)) * 4;
#pragma unroll
        for (int s = 0; s < 8; s++) {
            f16x8 v = *(const f16x8*)(qb + (bq + (s >> 1)) * 512 + ((s & 1) * 2 + halfl) * 128 + (lane & 15) * 8);
            aq[s] = v * (f16)(0.08838834764831845f * 1.4426950408889634f);
        }
    }

    float m_i = -1e30f, l_i = 0.f;
    f32x16 oacc[4] = {};   // O^T: 4 d-tiles of 32, col q

    // stage K/V tile mc into buffer (wave 0,1: K ; wave 2,3: V), pure gld16
    auto stage = [&](int mc, f16* dst) {
        if (wv < 2) {
            const f16* src = kb + (size_t)(mc >> 1) * 16384 + (size_t)(mc & 1) * 512;
#pragma unroll
            for (int i = 0; i < 8; i++)
                gld16(src + (size_t)(wv * 8 + i) * 1024 + lane * 8, dst + (wv * 8 + i) * 512);
        } else {
            const f16* src = vb + (size_t)mc * 8192;
#pragma unroll
            for (int i = 0; i < 8; i++)
                gld16(src + (size_t)((wv - 2) * 8 + i) * 512 + lane * 8, dst + 8192 + ((wv - 2) * 8 + i) * 512);
        }
    };

    stage(0, smem);

    for (int mc = 0; mc < 16; mc++) {
        __syncthreads();                 // implicit vmcnt(0): tile mc resident, prior reads done
        f16* Kc = smem + (mc & 1) * 16384;
        f16* Vc = Kc + 8192;
        if (mc < 15) stage(mc + 1, smem + ((mc + 1) & 1) * 16384);

        // S^T = K Q^T : two 32x32 k-tiles, A = K (row=kpix, k=d), B = Q
        f32x16 st0 = {}, st1 = {};
#pragma unroll
        for (int s = 0; s < 8; s++) {
            f16x8 k0 = *(const f16x8*)&Kc[(s * 2 + halfl) * 512 + l31 * 8];
            f16x8 k1 = *(const f16x8*)&Kc[(s * 2 + halfl) * 512 + (32 + l31) * 8];
            st0 = __builtin_amdgcn_mfma_f32_32x32x16_f16(k0, aq[s], st0, 0, 0, 0);
            st1 = __builtin_amdgcn_mfma_f32_32x32x16_f16(k1, aq[s], st1, 0, 0, 0);
        }

        // online softmax (exp2 domain): in-lane tree over 32 vals + ONE shfl_xor(32)
        float a[16];
#pragma unroll
        for (int i = 0; i < 16; i++) a[i] = fmaxf(st0[i], st1[i]);
#pragma unroll
        for (int i = 0; i < 8; i++) a[i] = fmaxf(a[i], a[i + 8]);
#pragma unroll
        for (int i = 0; i < 4; i++) a[i] = fmaxf(a[i], a[i + 4]);
        float mx = fmaxf(fmaxf(a[0], a[1]), fmaxf(a[2], a[3]));
        mx = fmaxf(mx, __shfl_xor(mx, 32));

        bool full = !__all(mx <= m_i + 8.f);
        float mnew = m_i, alpha = 1.f;
        if (full) {
            mnew = fmaxf(m_i, mx);
            alpha = __builtin_amdgcn_exp2f(m_i - mnew);
            m_i = mnew;
        }

        float r[16];
#pragma unroll
        for (int i = 0; i < 16; i++) {
            float p0 = __builtin_amdgcn_exp2f(st0[i] - mnew);
            float p1 = __builtin_amdgcn_exp2f(st1[i] - mnew);
            st0[i] = p0; st1[i] = p1;
            r[i] = p0 + p1;
        }
#pragma unroll
        for (int i = 0; i < 8; i++) r[i] += r[i + 8];
#pragma unroll
        for (int i = 0; i < 4; i++) r[i] += r[i + 4];
        float rs = (r[0] + r[1]) + (r[2] + r[3]);
        rs += __shfl_xor(rs, 32);
        if (full) {
            l_i = l_i * alpha + rs;
#pragma unroll
            for (int dt = 0; dt < 4; dt++)
#pragma unroll
                for (int i = 0; i < 16; i++) oacc[dt][i] *= alpha;
        } else {
            l_i += rs;
        }

        // P store: rows kpix = kt*32 + g*8 + halfl*4 + r, col q = l31 (XOR-swizzled)
#pragma unroll
        for (int g = 0; g < 4; g++) {
            f16x4 pv0, pv1;
#pragma unroll
            for (int rr = 0; rr < 4; rr++) { pv0[rr] = (f16)st0[g * 4 + rr]; pv1[rr] = (f16)st1[g * 4 + rr]; }
            *(f16x4*)&Pw[l31 * 64 + ((g ^ (l31 & 7)) << 3) + (halfl << 2)] = pv0;
            *(f16x4*)&Pw[l31 * 64 + (((4 + g) ^ (l31 & 7)) << 3) + (halfl << 2)] = pv1;
        }

        // O^T += V^T P : A = V^T (row=d, k=kpix), B = P (col=q, k=kpix)
#pragma unroll
        for (int ks = 0; ks < 4; ks++) {
            f16x8 pf = *(const f16x8*)&Pw[l31 * 64 + (((ks * 2 + halfl) ^ (l31 & 7)) << 3)];
#pragma unroll
            for (int dt = 0; dt < 4; dt++) {
                f16x8 vf = *(const f16x8*)&Vc[(ks * 2 + halfl) * 1024 + (dt * 32 + l31) * 8];
                oacc[dt] = __builtin_amdgcn_mfma_f32_32x32x16_f16(vf, pf, oacc[dt], 0, 0, 0);
            }
        }
    }

    // epilogue: stage O (128 d x 128 q) into smem[0,16384) with XOR swizzle, then coalesced store
    __syncthreads();
    {
        float inv = 1.f / l_i;
        int n = wv * 32 + l31;
#pragma unroll
        for (int dt = 0; dt < 4; dt++)
#pragma unroll
            for (int g = 0; g < 4; g++) {
                f16x4 ov;
#pragma unroll
                for (int rr = 0; rr < 4; rr++) ov[rr] = (f16)(oacc[dt][g * 4 + rr] * inv);
                int cbl = dt * 4 + g;   // d-block of 8 (base d = dt*32 + g*8 + halfl*4)
                *(f16x4*)&smem[n * 128 + ((cbl ^ (n & 15)) << 3) + (halfl << 2)] = ov;
            }
    }
    __syncthreads();
    f16* ob = oT + ((size_t)(b * 8 + nt)) * 65536;
#pragma unroll
    for (int i = 0; i < 8; i++) {
        int cid = tid + i * 256;
        int cbl = cid >> 7, n = cid & 127;
        f16x8 v = *(const f16x8*)&smem[n * 128 + ((cbl ^ (n & 15)) << 3)];
        *(f16x8*)(ob + (size_t)(h * 16 + cbl) * 1024 + n * 8) = v;
    }
}

// ---------------- K4: proj GEMM + bias + residual -> fp32 out ----------------
__global__ __launch_bounds__(256, 3) void k_proj(const f16* __restrict__ wT, const float* __restrict__ bias,
                                                 const f16* __restrict__ oT, const float* __restrict__ x,
                                                 float* __restrict__ out) {
    int nt = blockIdx.x, ot = blockIdx.y, b = blockIdx.z;
    int n0 = nt * 128, o0 = ot * 128;
    __shared__ union SM {
        struct { f16 As[8192]; f16 Bs[8192]; } s;
        f16 Cs[128][136];
    } sm;
    __shared__ float biasS[128];
    if (threadIdx.x < 128) biasS[threadIdx.x] = bias[o0 + threadIdx.x];
    int tid = threadIdx.x, lane = tid & 63, wv = tid >> 6;
    int wr = wv >> 1, wc = wv & 1;
    int l15 = lane & 15, quad = lane >> 4;
    const f16* wA = wT + (size_t)ot * 65536;
    const f16* xB = oT + ((size_t)(b * 8 + nt)) * 65536;
    f32x4 acc[4][4] = {};
    for (int kk = 0; kk < CH; kk += 64) {
        __syncthreads();
        const f16* sa = wA + (size_t)(kk >> 3) * 1024;
        const f16* sb = xB + (size_t)(kk >> 3) * 1024;
#pragma unroll
        for (int i = 0; i < 4; i++) {
            int s = wv * 4 + i;
            gld16(sa + (size_t)(s * 64 + lane) * 8, sm.s.As + s * 512);
            gld16(sb + (size_t)(s * 64 + lane) * 8, sm.s.Bs + s * 512);
        }
        __syncthreads();
#pragma unroll
        for (int dk = 0; dk < 2; dk++) {
            f16x8 af[4], bf[4];
#pragma unroll
            for (int t = 0; t < 4; t++) {
                af[t] = *(const f16x8*)(sm.s.As + (dk * 4 + quad) * 1024 + (wr * 64 + t * 16 + l15) * 8);
                bf[t] = *(const f16x8*)(sm.s.Bs + (dk * 4 + quad) * 1024 + (wc * 64 + t * 16 + l15) * 8);
            }
#pragma unroll
            for (int tm = 0; tm < 4; tm++)
#pragma unroll
                for (int tn = 0; tn < 4; tn++)
                    acc[tm][tn] = __builtin_amdgcn_mfma_f32_16x16x32_f16(af[tm], bf[tn], acc[tm][tn], 0, 0, 0);
        }
    }
    __syncthreads();
#pragma unroll
    for (int tm = 0; tm < 4; tm++)
#pragma unroll
        for (int tn = 0; tn < 4; tn++)
#pragma unroll
            for (int r = 0; r < 4; r++) {
                int o = wr * 64 + tm * 16 + quad * 4 + r;
                int n = wc * 64 + tn * 16 + l15;
                sm.Cs[o][n] = (f16)(acc[tm][tn][r] + biasS[o]);
            }
    __syncthreads();
#pragma unroll
    for (int i = 0; i < 8; i++) {
        int cid = tid + i * 256;
        int row = cid >> 4, off = (cid & 15) * 8;
        f16x8 v = *(const f16x8*)&sm.Cs[row][off];
        size_t gofs = ((size_t)(b * CH) + o0 + row) * NPIX + n0 + off;
        const float* xp = x + gofs;
        float* op = out + gofs;
        f32x4 o0v, o1v;
        o0v.x = xp[0] + (float)v[0]; o0v.y = xp[1] + (float)v[1];
        o0v.z = xp[2] + (float)v[2]; o0v.w = xp[3] + (float)v[3];
        o1v.x = xp[4] + (float)v[4]; o1v.y = xp[5] + (float)v[5];
        o1v.z = xp[6] + (float)v[6]; o1v.w = xp[7] + (float)v[7];
        *(f32x4*)op = o0v; *(f32x4*)(op + 4) = o1v;
    }
}

extern "C" void kernel_launch(void* const* d_in, const int* in_sizes, int n_in,
                              void* d_out, int out_size, void* d_ws, size_t ws_size,
                              hipStream_t stream) {
    const float* x     = (const float*)d_in[0];
    const float* gamma = (const float*)d_in[1];
    const float* beta  = (const float*)d_in[2];
    const float* wqkv  = (const float*)d_in[3];
    const float* bqkv  = (const float*)d_in[4];
    const float* wproj = (const float*)d_in[5];
    const float* bproj = (const float*)d_in[6];
    float* out = (float*)d_out;

    char* p = (char*)d_ws;
    f16* wqT = (f16*)p;           p += (size_t)3 * CH * CH * 2;
    f16* wpT = (f16*)p;           p += (size_t)CH * CH * 2;
    f16* xnT = (f16*)p;           p += (size_t)BATCH * NPIX * CH * 2;
    f16* qF  = (f16*)p;           p += (size_t)BATCH * HEADS * NPIX * HD * 2;
    f16* kTl = (f16*)p;           p += (size_t)BATCH * HEADS * NPIX * HD * 2;
    f16* vTl = (f16*)p;           p += (size_t)BATCH * HEADS * NPIX * HD * 2;
    f16* oT  = (f16*)p;           p += (size_t)BATCH * NPIX * CH * 2;

    k_pre<<<dim3(896), 256, 0, stream>>>(x, gamma, beta, xnT, wqkv, wproj, wqT, wpT);
    k_qkv<<<dim3(8, 12, BATCH), 256, 0, stream>>>(wqT, bqkv, xnT, qF, kTl, vTl);

    hipFuncSetAttribute((const void*)k_attn, hipFuncAttributeMaxDynamicSharedMemorySize, 81920);
    k_attn<<<dim3(512), 256, 81920, stream>>>(qF, kTl, vTl, oT);

    k_proj<<<dim3(8, 4, BATCH), 256, 0, stream>>>(wpT, bproj, oT, x, out);
}